// Round 2
// baseline (267.822 us; speedup 1.0000x reference)
//
#include <hip/hip_runtime.h>

// D = H = W = 128, NUM_STEPS = 7 (MONAI DVF2DDF scaling-and-squaring)
#define DD 128
constexpr int NV = DD * DD * DD;           // 2,097,152 voxels
constexpr float SCALE = 1.0f / 128.0f;     // 2^-NUM_STEPS

// XCD-aware swizzle: hardware assigns block b -> XCD (b % 8) round-robin.
// Remap so XCD j owns a contiguous z-slab (16 z-slices = 3 MB < 4 MiB L2):
// gathers + next-step reads stay inside the XCD's private L2.
__device__ __forceinline__ int swizzle_block(int b) {
    return (b & 7) * 1024 + (b >> 3);      // bijection on [0, 8192)
}

__device__ __forceinline__ void unpack_zyx(int tid, int& z, int& y, int& x) {
    x = tid & (DD - 1);
    y = (tid >> 7) & (DD - 1);
    z = tid >> 14;
}

__device__ __forceinline__ float clampc(float v) {
    return fminf(fmaxf(v, 0.0f), (float)(DD - 1));
}

struct Corners {
    int i000, i001, i010, i011, i100, i101, i110, i111;
    float w000, w001, w010, w011, w100, w101, w110, w111;
};

__device__ __forceinline__ Corners corner_setup(float cz, float cy, float cx) {
    float z0f = floorf(cz), y0f = floorf(cy), x0f = floorf(cx);
    float wz = cz - z0f, wy = cy - y0f, wx = cx - x0f;
    int z0 = (int)z0f, y0 = (int)y0f, x0 = (int)x0f;
    int z1 = min(z0 + 1, DD - 1);
    int y1 = min(y0 + 1, DD - 1);
    int x1 = min(x0 + 1, DD - 1);
    float omz = 1.0f - wz, omy = 1.0f - wy, omx = 1.0f - wx;
    int zs0 = z0 << 14, zs1 = z1 << 14;
    int ys0 = y0 << 7,  ys1 = y1 << 7;
    Corners c;
    c.i000 = zs0 + ys0 + x0; c.i001 = zs0 + ys0 + x1;
    c.i010 = zs0 + ys1 + x0; c.i011 = zs0 + ys1 + x1;
    c.i100 = zs1 + ys0 + x0; c.i101 = zs1 + ys0 + x1;
    c.i110 = zs1 + ys1 + x0; c.i111 = zs1 + ys1 + x1;
    c.w000 = omz * omy * omx; c.w001 = omz * omy * wx;
    c.w010 = omz * wy * omx;  c.w011 = omz * wy * wx;
    c.w100 = wz * omy * omx;  c.w101 = wz * omy * wx;
    c.w110 = wz * wy * omx;   c.w111 = wz * wy * wx;
    return c;
}

// trilinear sample of interleaved [(DHW),3] field
__device__ __forceinline__ void trilerp3i(const float* __restrict__ src,
                                          const Corners& c,
                                          float& r0, float& r1, float& r2) {
    const float* p000 = src + 3 * c.i000; const float* p001 = src + 3 * c.i001;
    const float* p010 = src + 3 * c.i010; const float* p011 = src + 3 * c.i011;
    const float* p100 = src + 3 * c.i100; const float* p101 = src + 3 * c.i101;
    const float* p110 = src + 3 * c.i110; const float* p111 = src + 3 * c.i111;
    r0 = c.w000*p000[0] + c.w001*p001[0] + c.w010*p010[0] + c.w011*p011[0]
       + c.w100*p100[0] + c.w101*p101[0] + c.w110*p110[0] + c.w111*p111[0];
    r1 = c.w000*p000[1] + c.w001*p001[1] + c.w010*p010[1] + c.w011*p011[1]
       + c.w100*p100[1] + c.w101*p101[1] + c.w110*p110[1] + c.w111*p111[1];
    r2 = c.w000*p000[2] + c.w001*p001[2] + c.w010*p010[2] + c.w011*p011[2]
       + c.w100*p100[2] + c.w101*p101[2] + c.w110*p110[2] + c.w111*p111[2];
}

// ---------------------------------------------------------------------------
// step 1 fused with init: field F = SCALE*dvf (planar input).
// trilerp is linear in field values -> gather raw dvf, scale once.
// dst interleaved.
// ---------------------------------------------------------------------------
__global__ __launch_bounds__(256)
void step1_kernel(const float* __restrict__ dvf, float* __restrict__ dst) {
    int b = swizzle_block(blockIdx.x);
    int tid = b * 256 + threadIdx.x;
    int z, y, x;
    unpack_zyx(tid, z, y, x);

    float d0 = dvf[tid] * SCALE;
    float d1 = dvf[tid + NV] * SCALE;
    float d2 = dvf[tid + 2 * NV] * SCALE;

    Corners c = corner_setup(clampc((float)z + d0),
                             clampc((float)y + d1),
                             clampc((float)x + d2));

    float r0 = 0.f, r1 = 0.f, r2 = 0.f;
    {
        const float* s0 = dvf;
        const float* s1 = dvf + NV;
        const float* s2 = dvf + 2 * NV;
        r0 = c.w000*s0[c.i000] + c.w001*s0[c.i001] + c.w010*s0[c.i010] + c.w011*s0[c.i011]
           + c.w100*s0[c.i100] + c.w101*s0[c.i101] + c.w110*s0[c.i110] + c.w111*s0[c.i111];
        r1 = c.w000*s1[c.i000] + c.w001*s1[c.i001] + c.w010*s1[c.i010] + c.w011*s1[c.i011]
           + c.w100*s1[c.i100] + c.w101*s1[c.i101] + c.w110*s1[c.i110] + c.w111*s1[c.i111];
        r2 = c.w000*s2[c.i000] + c.w001*s2[c.i001] + c.w010*s2[c.i010] + c.w011*s2[c.i011]
           + c.w100*s2[c.i100] + c.w101*s2[c.i101] + c.w110*s2[c.i110] + c.w111*s2[c.i111];
    }

    float* p = dst + 3 * tid;
    p[0] = d0 + r0 * SCALE;
    p[1] = d1 + r1 * SCALE;
    p[2] = d2 + r2 * SCALE;
}

// ---------------------------------------------------------------------------
// steps 2..6: dst = src + warp(src, src), both interleaved
// ---------------------------------------------------------------------------
__global__ __launch_bounds__(256)
void step_kernel(const float* __restrict__ src, float* __restrict__ dst) {
    int b = swizzle_block(blockIdx.x);
    int tid = b * 256 + threadIdx.x;
    int z, y, x;
    unpack_zyx(tid, z, y, x);

    const float* s = src + 3 * tid;
    float d0 = s[0], d1 = s[1], d2 = s[2];

    Corners c = corner_setup(clampc((float)z + d0),
                             clampc((float)y + d1),
                             clampc((float)x + d2));
    float r0, r1, r2;
    trilerp3i(src, c, r0, r1, r2);

    float* p = dst + 3 * tid;
    p[0] = d0 + r0; p[1] = d1 + r1; p[2] = d2 + r2;
}

// ---------------------------------------------------------------------------
// step 7 fused with output warps: src = field after 6 steps (interleaved,
// living in the dvf output slot). Computes ddf = src + warp(src,src), writes
// planar ddf (slot 0), then warps moving_image (bilinear) and moving_label
// (nearest) with that ddf -> slots 1, 2. Writes never touch the gather src.
// ---------------------------------------------------------------------------
__global__ __launch_bounds__(256)
void step7_final_kernel(const float* __restrict__ src,
                        const float* __restrict__ mimg,
                        const float* __restrict__ mlab,
                        float* __restrict__ ddf_out,
                        float* __restrict__ pred_img,
                        float* __restrict__ pred_lab) {
    int b = swizzle_block(blockIdx.x);
    int tid = b * 256 + threadIdx.x;
    int z, y, x;
    unpack_zyx(tid, z, y, x);

    const float* s = src + 3 * tid;
    float d0 = s[0], d1 = s[1], d2 = s[2];

    Corners c = corner_setup(clampc((float)z + d0),
                             clampc((float)y + d1),
                             clampc((float)x + d2));
    float r0, r1, r2;
    trilerp3i(src, c, r0, r1, r2);

    r0 += d0; r1 += d1; r2 += d2;        // final ddf at this voxel
    ddf_out[tid]          = r0;
    ddf_out[tid + NV]     = r1;
    ddf_out[tid + 2 * NV] = r2;

    float cz = clampc((float)z + r0);
    float cy = clampc((float)y + r1);
    float cx = clampc((float)x + r2);

    // bilinear warp of moving_image
    {
        Corners g = corner_setup(cz, cy, cx);
        float v = g.w000*mimg[g.i000] + g.w001*mimg[g.i001]
                + g.w010*mimg[g.i010] + g.w011*mimg[g.i011]
                + g.w100*mimg[g.i100] + g.w101*mimg[g.i101]
                + g.w110*mimg[g.i110] + g.w111*mimg[g.i111];
        pred_img[tid] = v;
    }
    // nearest warp of moving_label (jnp.round = ties-to-even = rintf)
    {
        int zi = (int)rintf(cz);
        int yi = (int)rintf(cy);
        int xi = (int)rintf(cx);
        pred_lab[tid] = mlab[(zi << 14) + (yi << 7) + xi];
    }
}

// ---------------------------------------------------------------------------
// dvf pass-through, float4-vectorized (overwrites the ping-pong scratch
// in the dvf slot; ordered after step7_final by stream serialization)
// ---------------------------------------------------------------------------
__global__ __launch_bounds__(256)
void copy_dvf_kernel(const float4* __restrict__ dvf, float4* __restrict__ dvf_out) {
    int tid = blockIdx.x * blockDim.x + threadIdx.x;
    dvf_out[tid] = dvf[tid];
}

extern "C" void kernel_launch(void* const* d_in, const int* in_sizes, int n_in,
                              void* d_out, int out_size, void* d_ws, size_t ws_size,
                              hipStream_t stream) {
    const float* dvf  = (const float*)d_in[0];
    const float* mimg = (const float*)d_in[1];
    // d_in[2] = fixed_image: unused by the reference outputs
    const float* mlab = (const float*)d_in[3];

    float* out      = (float*)d_out;
    float* ddf_out  = out;              // slot 0: ddf  [3,D,H,W]
    float* pred_img = out + 3 * NV;     // slot 1
    float* pred_lab = out + 4 * NV;     // slot 2
    float* dvf_out  = out + 5 * NV;     // slot 3: dvf pass-through

    // Ping-pong inside d_out. Parity chosen so the step-7 gather source is
    // the dvf slot (A), disjoint from step7_final's writes (slots 0,1,2).
    float* A = dvf_out;                 // [5NV, 8NV)
    float* B = ddf_out;                 // [0, 3NV)

    dim3 block(256);
    dim3 grid(NV / 256);                // 8192 blocks

    step1_kernel<<<grid, block, 0, stream>>>(dvf, B);        // init+step1 -> B
    step_kernel<<<grid, block, 0, stream>>>(B, A);           // step 2
    step_kernel<<<grid, block, 0, stream>>>(A, B);           // step 3
    step_kernel<<<grid, block, 0, stream>>>(B, A);           // step 4
    step_kernel<<<grid, block, 0, stream>>>(A, B);           // step 5
    step_kernel<<<grid, block, 0, stream>>>(B, A);           // step 6 -> A (dvf slot)
    step7_final_kernel<<<grid, block, 0, stream>>>(A, mimg, mlab,
                                                   ddf_out, pred_img, pred_lab);
    copy_dvf_kernel<<<3 * NV / (4 * 256), block, 0, stream>>>(
        (const float4*)dvf, (float4*)dvf_out);
}